// Round 14
// baseline (175.558 us; speedup 1.0000x reference)
//
#include <hip/hip_runtime.h>
#include <stdint.h>

#define Bn 8
#define Nn 1024
#define Fn 64
#define Tn 32
#define Kn 3
#define On 64
#define Rn (Kn * Nn)   // 3072 reduction dim (k,j)
#define Cn (On * Tn)   // 2048 output cols (o,t)
#define NT (Rn / 64)   // 48 K-tiles of BK=64

typedef __bf16 bf16x8 __attribute__((ext_vector_type(8)));
typedef float f32x4 __attribute__((ext_vector_type(4)));
typedef __attribute__((address_space(1))) void gvoid;
typedef __attribute__((address_space(3))) void lvoid;

union BF8 { bf16x8 v; ushort s[8]; uint4 q; };

static __device__ __forceinline__ ushort f2bf(float f) {
  uint32_t u = __float_as_uint(f);
  return (ushort)((u + 0x7FFFu + ((u >> 16) & 1u)) >> 16);
}

static __device__ __forceinline__ void glds(const ushort* g, ushort* l) {
  __builtin_amdgcn_global_load_lds((gvoid*)g, (lvoid*)l, 16, 0, 0);
}

// K0: ThetaT[k][o][f] = Theta[k][f][o], bf16 (separate — R12 fold was a straggler).
__global__ void k_thetaT(const float* __restrict__ Theta, ushort* __restrict__ ThT) {
  int idx = blockIdx.x * 256 + threadIdx.x;
  if (idx < Kn * On * Fn) {
    int k = idx / (On * Fn);
    int rem = idx % (On * Fn);
    int o = rem / Fn, f = rem % Fn;
    ThT[idx] = f2bf(Theta[(k * Fn + f) * On + o]);
  }
}

// K1: Wt[b][i][k*Nn+j] = cheb[k][j][i] * att[b][j][i], bf16 (R9/R13 measured).
__global__ __launch_bounds__(256) void k_prepW(const float* __restrict__ att,
                                               const float* __restrict__ cheb,
                                               ushort* __restrict__ Wt) {
  __shared__ float chebT[Kn][64][33];
  __shared__ float attT[64][33];
  int i0 = blockIdx.x * 64, j0 = blockIdx.y * 32;
  int tid = threadIdx.x;
  int il = tid & 63, jr = tid >> 6;
  int jc = tid & 3, iw = tid >> 2;

#pragma unroll
  for (int k = 0; k < Kn; k++)
#pragma unroll
    for (int p = 0; p < 8; p++) {
      int j = jr + p * 4;
      chebT[k][il][j] = cheb[((size_t)k * Nn + j0 + j) * Nn + i0 + il];
    }

  for (int b = 0; b < Bn; b++) {
    __syncthreads();
#pragma unroll
    for (int p = 0; p < 8; p++) {
      int j = jr + p * 4;
      attT[il][j] = att[((size_t)b * Nn + j0 + j) * Nn + i0 + il];
    }
    __syncthreads();
#pragma unroll
    for (int k = 0; k < Kn; k++) {
      ushort tmp[8];
#pragma unroll
      for (int q = 0; q < 8; q++)
        tmp[q] = f2bf(attT[iw][jc * 8 + q] * chebT[k][iw][jc * 8 + q]);
      *(uint4*)&Wt[((size_t)b * Nn + i0 + iw) * Rn + (size_t)k * Nn + j0 + jc * 8] =
          *(const uint4*)tmp;
    }
  }
}

// K2: Y_T[b][c][k*Nn+j] = sum_f ThT[k][o][f]*x[b][j][f][t] (R11/R13 measured).
__global__ __launch_bounds__(512) void k_prepY(const float* __restrict__ x,
                                               const ushort* __restrict__ ThT,
                                               ushort* __restrict__ Yt) {
  __shared__ ushort ylds[1024 * 32];
  int jt = blockIdx.x, b = blockIdx.y;
  int j0 = jt * 32;
  int tid = threadIdx.x;
  int lane = tid & 63, w = tid >> 6;
  int l15 = lane & 15, l4 = lane >> 4;

  BF8 bfr[4][2][2];
#pragma unroll
  for (int jj = 0; jj < 4; jj++) {
    const float* xp = x + ((size_t)b * Nn + (j0 + w * 4 + jj)) * (Fn * Tn);
#pragma unroll
    for (int ks = 0; ks < 2; ks++)
#pragma unroll
      for (int tf = 0; tf < 2; tf++) {
        int t = tf * 16 + l15;
        int fb = ks * 32 + l4 * 8;
#pragma unroll
        for (int e = 0; e < 8; e++)
          bfr[jj][ks][tf].s[e] = f2bf(xp[(fb + e) * Tn + t]);
      }
  }

  for (int k = 0; k < Kn; k++) {
    for (int h = 0; h < 2; h++) {
      BF8 afr[2][2];
#pragma unroll
      for (int o2 = 0; o2 < 2; o2++)
#pragma unroll
        for (int ks = 0; ks < 2; ks++) {
          int o = h * 32 + o2 * 16 + l15;
          afr[o2][ks].q = *(const uint4*)&ThT[((size_t)k * On + o) * Fn + ks * 32 + l4 * 8];
        }
      uint32_t* y32 = (uint32_t*)ylds;
#pragma unroll
      for (int jp = 0; jp < 2; jp++) {
        f32x4 acc[2][2][2] = {};
#pragma unroll
        for (int j2 = 0; j2 < 2; j2++)
#pragma unroll
          for (int ks = 0; ks < 2; ks++)
#pragma unroll
            for (int o2 = 0; o2 < 2; o2++)
#pragma unroll
              for (int tf = 0; tf < 2; tf++)
                acc[j2][o2][tf] = __builtin_amdgcn_mfma_f32_16x16x32_bf16(
                    afr[o2][ks].v, bfr[jp * 2 + j2][ks][tf].v, acc[j2][o2][tf], 0, 0, 0);
#pragma unroll
        for (int o2 = 0; o2 < 2; o2++)
#pragma unroll
          for (int tf = 0; tf < 2; tf++)
#pragma unroll
            for (int q = 0; q < 4; q++) {
              int cl = (o2 * 16 + l4 * 4 + q) * Tn + tf * 16 + l15;
              uint32_t pk = (uint32_t)f2bf(acc[0][o2][tf][q]) |
                            ((uint32_t)f2bf(acc[1][o2][tf][q]) << 16);
              y32[cl * 16 + w * 2 + jp] = pk;
            }
      }
      __syncthreads();
      const uint4* yl4 = (const uint4*)ylds;
      uint4* Yt4 = (uint4*)Yt;
      int e4 = tid & 3, r4 = tid >> 2;
      for (int pass = 0; pass < 8; pass++) {
        int cl = pass * 128 + r4;
        size_t off = ((size_t)b * Cn + (size_t)(h * 1024 + cl)) * Rn + (size_t)k * Nn + j0;
        Yt4[off / 8 + e4] = yl4[cl * 4 + e4];
      }
      __syncthreads();
    }
  }
}

// K3 R14: HALF-SCALE R5 — 128x128 tile, BK=64, 4 waves (2Mx2N), 64 KB LDS
// -> 2 independent blocks/CU (TLP: one block's barrier drain overlaps the
// other's MFMA phase, m114 mechanism). Schedule = R5's TILE verbatim at
// 2-glds-per-stage granularity; vmcnt queue re-traced (6->10->6 steady,
// VMC 4/4/6, tails 4/2/0). Half h = rows [h*32,h*32+32) U [64+h*32,96+h*32).
__global__ __launch_bounds__(256, 2) void k_gemm(const ushort* __restrict__ Wt,
                                                 const ushort* __restrict__ Yt,
                                                 float* __restrict__ out) {
  extern __shared__ __align__(16) ushort smem[];
  ushort* As = smem;            // 2 bufs x 2 halves x 64x64 = 16384 elems
  ushort* Bs = smem + 16384;

  int g = blockIdx.x;
  int b = g & 7, slot = g >> 3;             // 128 slots per b
  int i0 = (slot & 7) * 128, c0 = (slot >> 3) * 128;
  int tid = threadIdx.x, lane = tid & 63, w = tid >> 6;   // w in [0,4)
  int l15 = lane & 15, l4 = lane >> 4;
  int wm = w >> 1, wn = w & 1;

  const ushort* Ab = Wt + ((size_t)b * Nn + i0) * Rn;
  const ushort* Bb = Yt + ((size_t)b * Cn + c0) * Rn;

  int srcC = (((lane & 7) ^ (lane >> 3)) * 8);
  int arow0 = w * 8 + (lane >> 3);          // [0,32)

  int aL = (wm * 32 + l15) * 64;
  int bL = (wn * 32 + l15) * 64;
  int x7 = l15 & 7;
  int colx0 = ((l4) ^ x7) * 8;
  int colx1 = ((4 + l4) ^ x7) * 8;

  f32x4 acc[4][4] = {};
  BF8 afX[2][2], afY[2][2];   // A half0 / half1 frag sets (m0-1 / m2-3)
  BF8 bfX[2][2], bfY[2][2];   // B half0 / half1 (n0-1 / n2-3)

#define MFMA_(a_, b_, c_) __builtin_amdgcn_mfma_f32_16x16x32_bf16((a_), (b_), (c_), 0, 0, 0)
#define BAR() asm volatile("s_barrier" ::: "memory")
#define PRIO1 __builtin_amdgcn_s_setprio(1)
#define PRIO0 __builtin_amdgcn_s_setprio(0)
#define VMC(n_) asm volatile("s_waitcnt vmcnt(" #n_ ")" ::: "memory")

#define STAGE_A(t_, h_) { int bo_ = ((t_) & 1) * 8192 + (h_) * 4096 + w * 512; \
    const ushort* gp_ = Ab + (size_t)(arow0 + (h_) * 32) * Rn + (t_) * 64 + srcC; \
    glds(gp_, As + bo_); \
    glds(gp_ + 64 * (size_t)Rn, As + bo_ + 2048); }
#define STAGE_B(t_, h_) { int bo_ = ((t_) & 1) * 8192 + (h_) * 4096 + w * 512; \
    const ushort* gp_ = Bb + (size_t)(arow0 + (h_) * 32) * Rn + (t_) * 64 + srcC; \
    glds(gp_, Bs + bo_); \
    glds(gp_ + 64 * (size_t)Rn, Bs + bo_ + 2048); }

#define RD_A(DST_, bo_, mh_) { _Pragma("unroll") for (int mm = 0; mm < 2; mm++) { \
    int ba_ = (bo_) + (mh_) * 4096 + aL + mm * 1024; \
    DST_[mm][0].q = *(const uint4*)&As[ba_ + colx0]; \
    DST_[mm][1].q = *(const uint4*)&As[ba_ + colx1]; } }
#define RD_B(DST_, bo_, nh_) { _Pragma("unroll") for (int nn = 0; nn < 2; nn++) { \
    int bb_ = (bo_) + (nh_) * 4096 + bL + nn * 1024; \
    DST_[nn][0].q = *(const uint4*)&Bs[bb_ + colx0]; \
    DST_[nn][1].q = *(const uint4*)&Bs[bb_ + colx1]; } }

#define MMC(AF_, BF_, MO_, NO_) { _Pragma("unroll") for (int ks = 0; ks < 2; ks++) \
    _Pragma("unroll") for (int mm = 0; mm < 2; mm++) \
      _Pragma("unroll") for (int nn = 0; nn < 2; nn++) \
        acc[(MO_) + mm][(NO_) + nn] = MFMA_(AF_[mm][ks].v, BF_[nn][ks].v, acc[(MO_) + mm][(NO_) + nn]); }

  STAGE_A(0, 0); STAGE_B(0, 0); STAGE_B(0, 1); STAGE_A(0, 1); STAGE_A(1, 0);
  VMC(6); BAR();
  RD_A(afX, 0, 0); RD_B(bfX, 0, 0);

#define TILE(t_, S0_, S1_, S2_, W0_, W1_, W3_, LAST_) { \
    int bo_c = ((t_) & 1) * 8192; \
    VMC(W0_); BAR(); \
    RD_B(bfY, bo_c, 1); \
    if (S0_) STAGE_B((t_) + 1, 0); \
    PRIO1; MMC(afX, bfX, 0, 0); PRIO0; \
    VMC(W1_); BAR(); \
    RD_A(afY, bo_c, 1); \
    if (S1_) { STAGE_B((t_) + 1, 1); STAGE_A((t_) + 1, 1); } \
    PRIO1; MMC(afX, bfY, 0, 2); PRIO0; \
    if (S2_) STAGE_A((t_) + 2, 0); \
    PRIO1; MMC(afY, bfX, 2, 0); PRIO0; \
    if (!(LAST_)) { VMC(W3_); BAR(); \
      RD_A(afX, bo_c ^ 8192, 0); RD_B(bfX, bo_c ^ 8192, 0); } \
    PRIO1; MMC(afY, bfY, 2, 2); PRIO0; \
  }

  for (int t = 0; t < NT - 2; ++t)
    TILE(t, 1, 1, 1, 4, 4, 6, 0);
  TILE(NT - 2, 1, 1, 0, 4, 4, 4, 0);
  TILE(NT - 1, 0, 0, 0, 2, 0, 0, 1);

#undef TILE
#undef MMC
#undef RD_B
#undef RD_A
#undef STAGE_B
#undef STAGE_A
#undef VMC

  float* ob = out + (size_t)b * Nn * Cn;
#pragma unroll
  for (int m = 0; m < 4; m++) {
    int i = i0 + wm * 64 + (m >> 1) * 32 + (m & 1) * 16 + l4 * 4;
#pragma unroll
    for (int n = 0; n < 4; n++) {
      int c = c0 + wn * 64 + (n >> 1) * 32 + (n & 1) * 16 + l15;
#pragma unroll
      for (int q = 0; q < 4; q++)
        ob[(size_t)(i + q) * Cn + c] = fmaxf(acc[m][n][q], 0.0f);
    }
  }
}

extern "C" void kernel_launch(void* const* d_in, const int* in_sizes, int n_in,
                              void* d_out, int out_size, void* d_ws, size_t ws_size,
                              hipStream_t stream) {
  const float* x     = (const float*)d_in[0];  // (B,N,F,T)
  const float* att   = (const float*)d_in[1];  // (B,N,N)
  const float* cheb  = (const float*)d_in[2];  // (K,N,N)
  const float* Theta = (const float*)d_in[3];  // (K,F,O)
  float* out = (float*)d_out;                  // (B,N,O,T)

  char* ws = (char*)d_ws;
  ushort* ThT = (ushort*)ws;
  ushort* Wt  = (ushort*)(ws + 65536);
  ushort* Yt  = (ushort*)(ws + 65536 + 50331648ull);

  hipFuncSetAttribute((const void*)k_gemm, hipFuncAttributeMaxDynamicSharedMemorySize, 65536);

  k_thetaT<<<48, 256, 0, stream>>>(Theta, ThT);
  k_prepW<<<dim3(16, 32), 256, 0, stream>>>(att, cheb, Wt);
  k_prepY<<<dim3(32, 8), 512, 0, stream>>>(x, ThT, Yt);
  k_gemm<<<1024, 256, 65536, stream>>>(Wt, Yt, out);
}

// Round 15
// 152.020 us; speedup vs baseline: 1.1548x; 1.1548x over previous
//
#include <hip/hip_runtime.h>
#include <stdint.h>

#define Bn 8
#define Nn 1024
#define Fn 64
#define Tn 32
#define Kn 3
#define On 64
#define Rn (Kn * Nn)   // 3072 reduction dim (k,j)
#define Cn (On * Tn)   // 2048 output cols (o,t)
#define NT (Rn / 64)   // 48 K-tiles of BK=64

typedef __bf16 bf16x8 __attribute__((ext_vector_type(8)));
typedef float f32x4 __attribute__((ext_vector_type(4)));
typedef __attribute__((address_space(1))) void gvoid;
typedef __attribute__((address_space(3))) void lvoid;

union BF8 { bf16x8 v; ushort s[8]; uint4 q; };

static __device__ __forceinline__ ushort f2bf(float f) {
  uint32_t u = __float_as_uint(f);
  return (ushort)((u + 0x7FFFu + ((u >> 16) & 1u)) >> 16);
}

static __device__ __forceinline__ void glds(const ushort* g, ushort* l) {
  __builtin_amdgcn_global_load_lds((gvoid*)g, (lvoid*)l, 16, 0, 0);
}

// K0: ThetaT[k][o][f] = Theta[k][f][o], bf16. Separate kernel — R12 showed
// folding this into one prepW block creates an ~8us straggler.
__global__ void k_thetaT(const float* __restrict__ Theta, ushort* __restrict__ ThT) {
  int idx = blockIdx.x * 256 + threadIdx.x;
  if (idx < Kn * On * Fn) {
    int k = idx / (On * Fn);
    int rem = idx % (On * Fn);
    int o = rem / Fn, f = rem % Fn;
    ThT[idx] = f2bf(Theta[(k * Fn + f) * On + o]);
  }
}

// K1: Wt[b][i][k*Nn+j] = cheb[k][j][i] * att[b][j][i], bf16 (R9/R13 measured).
__global__ __launch_bounds__(256) void k_prepW(const float* __restrict__ att,
                                               const float* __restrict__ cheb,
                                               ushort* __restrict__ Wt) {
  __shared__ float chebT[Kn][64][33];
  __shared__ float attT[64][33];
  int i0 = blockIdx.x * 64, j0 = blockIdx.y * 32;
  int tid = threadIdx.x;
  int il = tid & 63, jr = tid >> 6;
  int jc = tid & 3, iw = tid >> 2;

#pragma unroll
  for (int k = 0; k < Kn; k++)
#pragma unroll
    for (int p = 0; p < 8; p++) {
      int j = jr + p * 4;
      chebT[k][il][j] = cheb[((size_t)k * Nn + j0 + j) * Nn + i0 + il];
    }

  for (int b = 0; b < Bn; b++) {
    __syncthreads();
#pragma unroll
    for (int p = 0; p < 8; p++) {
      int j = jr + p * 4;
      attT[il][j] = att[((size_t)b * Nn + j0 + j) * Nn + i0 + il];
    }
    __syncthreads();
#pragma unroll
    for (int k = 0; k < Kn; k++) {
      ushort tmp[8];
#pragma unroll
      for (int q = 0; q < 8; q++)
        tmp[q] = f2bf(attT[iw][jc * 8 + q] * chebT[k][iw][jc * 8 + q]);
      *(uint4*)&Wt[((size_t)b * Nn + i0 + iw) * Rn + (size_t)k * Nn + j0 + jc * 8] =
          *(const uint4*)tmp;
    }
  }
}

// K2: Y_T[b][c][k*Nn+j] = sum_f ThT[k][o][f]*x[b][j][f][t] (R11/R13 measured:
// jj-pair batching, packed ds_write_b32, uint4 global writes).
__global__ __launch_bounds__(512) void k_prepY(const float* __restrict__ x,
                                               const ushort* __restrict__ ThT,
                                               ushort* __restrict__ Yt) {
  __shared__ ushort ylds[1024 * 32];
  int jt = blockIdx.x, b = blockIdx.y;
  int j0 = jt * 32;
  int tid = threadIdx.x;
  int lane = tid & 63, w = tid >> 6;
  int l15 = lane & 15, l4 = lane >> 4;

  BF8 bfr[4][2][2];
#pragma unroll
  for (int jj = 0; jj < 4; jj++) {
    const float* xp = x + ((size_t)b * Nn + (j0 + w * 4 + jj)) * (Fn * Tn);
#pragma unroll
    for (int ks = 0; ks < 2; ks++)
#pragma unroll
      for (int tf = 0; tf < 2; tf++) {
        int t = tf * 16 + l15;
        int fb = ks * 32 + l4 * 8;
#pragma unroll
        for (int e = 0; e < 8; e++)
          bfr[jj][ks][tf].s[e] = f2bf(xp[(fb + e) * Tn + t]);
      }
  }

  for (int k = 0; k < Kn; k++) {
    for (int h = 0; h < 2; h++) {
      BF8 afr[2][2];
#pragma unroll
      for (int o2 = 0; o2 < 2; o2++)
#pragma unroll
        for (int ks = 0; ks < 2; ks++) {
          int o = h * 32 + o2 * 16 + l15;
          afr[o2][ks].q = *(const uint4*)&ThT[((size_t)k * On + o) * Fn + ks * 32 + l4 * 8];
        }
      uint32_t* y32 = (uint32_t*)ylds;
#pragma unroll
      for (int jp = 0; jp < 2; jp++) {
        f32x4 acc[2][2][2] = {};  // [j2][o2][tf]
#pragma unroll
        for (int j2 = 0; j2 < 2; j2++)
#pragma unroll
          for (int ks = 0; ks < 2; ks++)
#pragma unroll
            for (int o2 = 0; o2 < 2; o2++)
#pragma unroll
              for (int tf = 0; tf < 2; tf++)
                acc[j2][o2][tf] = __builtin_amdgcn_mfma_f32_16x16x32_bf16(
                    afr[o2][ks].v, bfr[jp * 2 + j2][ks][tf].v, acc[j2][o2][tf], 0, 0, 0);
#pragma unroll
        for (int o2 = 0; o2 < 2; o2++)
#pragma unroll
          for (int tf = 0; tf < 2; tf++)
#pragma unroll
            for (int q = 0; q < 4; q++) {
              int cl = (o2 * 16 + l4 * 4 + q) * Tn + tf * 16 + l15;
              uint32_t pk = (uint32_t)f2bf(acc[0][o2][tf][q]) |
                            ((uint32_t)f2bf(acc[1][o2][tf][q]) << 16);
              y32[cl * 16 + w * 2 + jp] = pk;
            }
      }
      __syncthreads();
      const uint4* yl4 = (const uint4*)ylds;
      uint4* Yt4 = (uint4*)Yt;
      int e4 = tid & 3, r4 = tid >> 2;
      for (int pass = 0; pass < 8; pass++) {
        int cl = pass * 128 + r4;
        size_t off = ((size_t)b * Cn + (size_t)(h * 1024 + cl)) * Rn + (size_t)k * Nn + j0;
        Yt4[off / 8 + e4] = yl4[cl * 4 + e4];
      }
      __syncthreads();
    }
  }
}

// K3: 256x256 tile, BK=64, 8 waves (2Mx4N), 2-deep K-tile dbuf, XOR-swizzled LDS.
// R5 EXACT — PINNED (96.0/96.2/96.3/96.4/96.6 us across R5/R9/R10/R12/R13,
// MfmaUtil 47.5%, 0 bank conflicts). Falsified alternatives: 6 barrier-phase
// schedules (108-129 us), direct-global B (155 us), half-tile 2-blocks/CU TLP
// (123.6 us, FETCH +33%). Do not revisit.
__global__ __launch_bounds__(512, 2) void k_gemm(const ushort* __restrict__ Wt,
                                                 const ushort* __restrict__ Yt,
                                                 float* __restrict__ out) {
  extern __shared__ __align__(16) ushort smem[];
  ushort* As = smem;           // 2 bufs x 2 halves x 128x64
  ushort* Bs = smem + 32768;

  int g = blockIdx.x;
  int b = g & 7, slot = g >> 3;
  int i0 = (slot & 3) * 256, c0 = (slot >> 2) * 256;
  int tid = threadIdx.x, lane = tid & 63, w = tid >> 6;
  int l15 = lane & 15, l4 = lane >> 4;
  int wm = w >> 2, wn = w & 3;

  const ushort* Ab = Wt + ((size_t)b * Nn + i0) * Rn;
  const ushort* Bb = Yt + ((size_t)b * Cn + c0) * Rn;

  int srcC = (((lane & 7) ^ (lane >> 3)) * 8);
  int arow0 = w * 8 + (lane >> 3);
  int brow0 = (w >> 2) * 64 + (w & 3) * 8 + (lane >> 3);

  int aL = (wm * 64 + l15) * 64;
  int bL = (wn * 32 + l15) * 64;
  int x7 = l15 & 7;
  int colx0 = ((l4) ^ x7) * 8;
  int colx1 = ((4 + l4) ^ x7) * 8;

  f32x4 acc[8][4] = {};
  BF8 afX[4][2], afY[4][2];
  BF8 bfX[2][2], bfY[2][2];

#define MFMA_(a_, b_, c_) __builtin_amdgcn_mfma_f32_16x16x32_bf16((a_), (b_), (c_), 0, 0, 0)
#define BAR() asm volatile("s_barrier" ::: "memory")
#define PRIO1 __builtin_amdgcn_s_setprio(1)
#define PRIO0 __builtin_amdgcn_s_setprio(0)
#define VMC(n_) asm volatile("s_waitcnt vmcnt(" #n_ ")" ::: "memory")

#define STAGE_A(t_, h_) { int bo_ = ((t_) & 1) * 16384 + (h_) * 8192 + w * 512; \
    const ushort* gp_ = Ab + (size_t)(arow0 + (h_) * 64) * Rn + (t_) * 64 + srcC; \
    glds(gp_, As + bo_); \
    glds(gp_ + 128 * (size_t)Rn, As + bo_ + 4096); }
#define STAGE_B(t_, h_) { int bo_ = ((t_) & 1) * 16384 + (h_) * 8192 + w * 512; \
    const ushort* gp_ = Bb + (size_t)(brow0 + (h_) * 32) * Rn + (t_) * 64 + srcC; \
    glds(gp_, Bs + bo_); \
    glds(gp_ + 128 * (size_t)Rn, Bs + bo_ + 4096); }

#define RD_A(DST_, bo_, mh_) { _Pragma("unroll") for (int m = 0; m < 4; m++) { \
    int ba_ = (bo_) + (mh_) * 8192 + aL + m * 1024; \
    DST_[m][0].q = *(const uint4*)&As[ba_ + colx0]; \
    DST_[m][1].q = *(const uint4*)&As[ba_ + colx1]; } }
#define RD_B(DST_, bo_, nh_) { _Pragma("unroll") for (int n = 0; n < 2; n++) { \
    int bb_ = (bo_) + (nh_) * 8192 + bL + n * 1024; \
    DST_[n][0].q = *(const uint4*)&Bs[bb_ + colx0]; \
    DST_[n][1].q = *(const uint4*)&Bs[bb_ + colx1]; } }

#define MMC(AF_, BF_, MO_, NO_) { _Pragma("unroll") for (int ks = 0; ks < 2; ks++) \
    _Pragma("unroll") for (int m = 0; m < 4; m++) \
      _Pragma("unroll") for (int n = 0; n < 2; n++) \
        acc[(MO_) + m][(NO_) + n] = MFMA_(AF_[m][ks].v, BF_[n][ks].v, acc[(MO_) + m][(NO_) + n]); }

  STAGE_A(0, 0); STAGE_B(0, 0); STAGE_B(0, 1); STAGE_A(0, 1); STAGE_A(1, 0);
  VMC(6); BAR();
  RD_A(afX, 0, 0); RD_B(bfX, 0, 0);

#define TILE(t_, S0_, S1_, S2_, W0_, W1_, W3_, LAST_) { \
    int bo_c = ((t_) & 1) * 16384; \
    VMC(W0_); BAR(); \
    RD_B(bfY, bo_c, 1); \
    if (S0_) STAGE_B((t_) + 1, 0); \
    PRIO1; MMC(afX, bfX, 0, 0); PRIO0; \
    VMC(W1_); BAR(); \
    RD_A(afY, bo_c, 1); \
    if (S1_) { STAGE_B((t_) + 1, 1); STAGE_A((t_) + 1, 1); } \
    PRIO1; MMC(afX, bfY, 0, 2); PRIO0; \
    if (S2_) STAGE_A((t_) + 2, 0); \
    PRIO1; MMC(afY, bfX, 4, 0); PRIO0; \
    if (!(LAST_)) { VMC(W3_); BAR(); \
      RD_A(afX, bo_c ^ 16384, 0); RD_B(bfX, bo_c ^ 16384, 0); } \
    PRIO1; MMC(afY, bfY, 4, 2); PRIO0; \
  }

  for (int t = 0; t < NT - 2; ++t)
    TILE(t, 1, 1, 1, 4, 4, 6, 0);
  TILE(NT - 2, 1, 1, 0, 4, 4, 4, 0);
  TILE(NT - 1, 0, 0, 0, 2, 0, 0, 1);

#undef TILE
#undef MMC
#undef RD_B
#undef RD_A
#undef STAGE_B
#undef STAGE_A
#undef VMC

  float* ob = out + (size_t)b * Nn * Cn;
#pragma unroll
  for (int m = 0; m < 8; m++) {
    int i = i0 + wm * 128 + m * 16 + l4 * 4;
#pragma unroll
    for (int n = 0; n < 4; n++) {
      int c = c0 + wn * 64 + n * 16 + l15;
#pragma unroll
      for (int q = 0; q < 4; q++)
        ob[(size_t)(i + q) * Cn + c] = fmaxf(acc[m][n][q], 0.0f);
    }
  }
}

extern "C" void kernel_launch(void* const* d_in, const int* in_sizes, int n_in,
                              void* d_out, int out_size, void* d_ws, size_t ws_size,
                              hipStream_t stream) {
  const float* x     = (const float*)d_in[0];  // (B,N,F,T)
  const float* att   = (const float*)d_in[1];  // (B,N,N)
  const float* cheb  = (const float*)d_in[2];  // (K,N,N)
  const float* Theta = (const float*)d_in[3];  // (K,F,O)
  float* out = (float*)d_out;                  // (B,N,O,T)

  char* ws = (char*)d_ws;
  ushort* ThT = (ushort*)ws;
  ushort* Wt  = (ushort*)(ws + 65536);
  ushort* Yt  = (ushort*)(ws + 65536 + 50331648ull);

  hipFuncSetAttribute((const void*)k_gemm, hipFuncAttributeMaxDynamicSharedMemorySize, 131072);

  k_thetaT<<<48, 256, 0, stream>>>(Theta, ThT);
  k_prepW<<<dim3(16, 32), 256, 0, stream>>>(att, cheb, Wt);
  k_prepY<<<dim3(32, 8), 512, 0, stream>>>(x, ThT, Yt);
  k_gemm<<<256, 512, 131072, stream>>>(Wt, Yt, out);
}